// Round 1
// baseline (100.453 us; speedup 1.0000x reference)
//
#include <hip/hip_runtime.h>

#define NB     32
#define NATOM  48
#define NGRID  128
#define NELEM  4
#define REC    16

#define MBTR_ELEMS (NB*NELEM*NELEM*NGRID)       /* 65536 */
#define DIV_PER_B  (NELEM*NELEM*NGRID*NATOM*3)  /* 294912 */

__device__ __constant__ const float kInvSigma   = 20.0f;          // 1/0.05
__device__ __constant__ const float kTScale     = 0.84932180580221964f; // sqrt(log2(e)/2)
__device__ __constant__ const float kInvSqrt2Pi = 0.3989422804014327f;

// Shared-memory layout for the accumulation phase (block = one (b, atom n))
struct SmemAcc {
    float4 pos[NATOM];
    int    zl[NATOM];
    int    cnt[4];
    int    order[NATOM];
    float4 recA[NATOM];   // {gf*is*c, gf*gf*is/c, wf*coef, u0}
    float2 recB[NATOM];   // {u1, u2}
};

// Computes A[h][e][c] = sum_{m: z[m]==e} s*u_c   and  M[h][e] = sum wf*gv
// for grid points k = t and k = t+64.  Also fills sm.zl.
__device__ __forceinline__ void mbtr_accum(SmemAcc& sm,
        const float* __restrict__ r, const int* __restrict__ z,
        const float* __restrict__ grid, int b, int n, int t,
        float (&A)[2][4][3], float (&M)[2][4], int (&soff)[5])
{
    if (t < NATOM) {
        sm.zl[t] = z[t];
        const float* rp = r + ((size_t)b * NATOM + t) * 3;
        sm.pos[t] = make_float4(rp[0], rp[1], rp[2], 0.f);
    }
    __syncthreads();

    if (t < 4) {
        int c = 0;
        for (int m = 0; m < NATOM; ++m) c += (m != n && sm.zl[m] == t) ? 1 : 0;
        sm.cnt[t] = c;
    }
    __syncthreads();

    // per-thread prefix offsets (registers, static-indexed after unroll)
    soff[0] = 0;
    #pragma unroll
    for (int e = 0; e < 4; ++e) soff[e + 1] = soff[e] + sm.cnt[e];

    if (t < 4) {
        int idx = 0;
        #pragma unroll
        for (int e = 0; e < 4; ++e) idx += (e < t) ? sm.cnt[e] : 0;
        for (int m = 0; m < NATOM; ++m)
            if (m != n && sm.zl[m] == t) sm.order[idx++] = m;
    }
    __syncthreads();

    const float4 rn = sm.pos[n];
    if (t < NATOM - 1) {
        const int   m  = sm.order[t];
        const float4 rm = sm.pos[m];
        const float ddx = rn.x - rm.x, ddy = rn.y - rm.y, ddz = rn.z - rm.z;
        const float d2 = ddx*ddx + ddy*ddy + ddz*ddz;
        const float gf = __builtin_amdgcn_rsqf(d2);   // 1/d
        const float d  = d2 * gf;
        const float wf = __expf(-d);                  // W_SCALE = 1
        const float dx = grid[1] - grid[0];
        const float coef = dx * kInvSqrt2Pi * kInvSigma;
        sm.recA[t] = make_float4(gf * (kInvSigma * kTScale),
                                 gf * gf * (kInvSigma / kTScale),
                                 wf * coef,
                                 ddx * gf);
        sm.recB[t] = make_float2(ddy * gf, ddz * gf);
    }
    __syncthreads();

    const float gkA = grid[t]      * (kInvSigma * kTScale);
    const float gkB = grid[t + 64] * (kInvSigma * kTScale);

    #pragma unroll
    for (int e = 0; e < 4; ++e) {
        const int beg = soff[e], end = soff[e + 1];
        for (int i = beg; i < end; ++i) {
            const float4 ra = sm.recA[i];
            const float2 rb = sm.recB[i];
            {   // k = t
                const float tt  = gkA - ra.x;            // t*c
                const float ex  = exp2f(-tt * tt);       // exp(-t^2/2)
                const float gvw = ra.z * ex;             // wf*gv
                M[0][e] += gvw;
                const float p = gvw * fmaf(tt, ra.y, 1.0f);  // -s
                A[0][e][0] = fmaf(-p, ra.w, A[0][e][0]);
                A[0][e][1] = fmaf(-p, rb.x, A[0][e][1]);
                A[0][e][2] = fmaf(-p, rb.y, A[0][e][2]);
            }
            {   // k = t + 64
                const float tt  = gkB - ra.x;
                const float ex  = exp2f(-tt * tt);
                const float gvw = ra.z * ex;
                M[1][e] += gvw;
                const float p = gvw * fmaf(tt, ra.y, 1.0f);
                A[1][e][0] = fmaf(-p, ra.w, A[1][e][0]);
                A[1][e][1] = fmaf(-p, rb.x, A[1][e][1]);
                A[1][e][2] = fmaf(-p, rb.y, A[1][e][2]);
            }
        }
    }
}

// ---------- K1: write compact records to workspace [b][k][n][16] ----------
__global__ __launch_bounds__(64)
void mbtr_k1(const float* __restrict__ r, const int* __restrict__ z,
             const float* __restrict__ grid, float* __restrict__ ws)
{
    const int n = blockIdx.x, b = blockIdx.y, t = threadIdx.x;
    __shared__ SmemAcc sm;
    float A[2][4][3] = {{{0.f}}};
    float M[2][4]    = {{0.f}};
    int soff[5];
    mbtr_accum(sm, r, z, grid, b, n, t, A, M, soff);

    #pragma unroll
    for (int h = 0; h < 2; ++h) {
        const int k = t + 64 * h;
        float tmp[REC];
        #pragma unroll
        for (int e = 0; e < 4; ++e) {
            #pragma unroll
            for (int c = 0; c < 3; ++c) tmp[e * 3 + c] = A[h][e][c];
            tmp[12 + e] = M[h][e];
        }
        float4* o4 = (float4*)(ws + (((size_t)b * NGRID + k) * NATOM + n) * REC);
        o4[0] = make_float4(tmp[0],  tmp[1],  tmp[2],  tmp[3]);
        o4[1] = make_float4(tmp[4],  tmp[5],  tmp[6],  tmp[7]);
        o4[2] = make_float4(tmp[8],  tmp[9],  tmp[10], tmp[11]);
        o4[3] = make_float4(tmp[12], tmp[13], tmp[14], tmp[15]);
    }
}

// ---------- K2: coalesced expansion records -> (mbtr, mbtr_div) ----------
__global__ __launch_bounds__(256)
void mbtr_k2(const int* __restrict__ z, const float* __restrict__ ws,
             float* __restrict__ out)
{
    const int kt = blockIdx.x;          // 16 tiles of 8 grid points
    const int b  = blockIdx.y;
    const int t  = threadIdx.x;
    const int k0 = kt * 8;

    __shared__ int    zl[NATOM];
    __shared__ float4 recs4[8 * NATOM * REC / 4];   // 24 KB
    float* recs = (float*)recs4;

    if (t < NATOM) zl[t] = z[t];
    const float4* w4 = (const float4*)(ws + ((size_t)b * NGRID + k0) * NATOM * REC);
    #pragma unroll
    for (int i = 0; i < 6; ++i) recs4[t + 256 * i] = w4[t + 256 * i];
    __syncthreads();

    // per-thread output map: q = t + 256*j covers (e1,e2,n,c), fixed across k
    int   adr1[9], adr2[9], P[9];
    float a1[9], a2[9];
    #pragma unroll
    for (int j = 0; j < 9; ++j) {
        const int q  = t + 256 * j;
        const int c  = q % 3;
        const int nn = (q / 3) % NATOM;
        const int e2 = (q / 144) & 3;
        const int e1 = q / 576;
        adr1[j] = nn * REC + e2 * 3 + c;
        adr2[j] = nn * REC + e1 * 3 + c;
        a1[j] = (zl[nn] == e1) ? 1.f : 0.f;
        a2[j] = (zl[nn] == e2) ? 1.f : 0.f;
        P[j]  = (e1 * 4 + e2) * (NGRID * NATOM * 3) + nn * 3 + c;
    }

    float* divout = out + MBTR_ELEMS + (size_t)b * DIV_PER_B;
    #pragma unroll
    for (int kk = 0; kk < 8; ++kk) {
        const float* rk = recs + kk * (NATOM * REC);
        const int k = k0 + kk;
        #pragma unroll
        for (int j = 0; j < 9; ++j) {
            divout[(size_t)(P[j] + k * (NATOM * 3))] =
                a1[j] * rk[adr1[j]] + a2[j] * rk[adr2[j]];
        }
        if (t < 64) {   // wave 0: mbtr row for this k
            const int e1 = t >> 4, e2 = (t >> 2) & 3, part = t & 3;
            float s = 0.f;
            for (int nn = part; nn < NATOM; nn += 4)
                s += (zl[nn] == e1) ? rk[nn * REC + 12 + e2] : 0.f;
            s += __shfl_xor(s, 1);
            s += __shfl_xor(s, 2);
            if (part == 0)
                out[((size_t)b * 16 + (e1 * 4 + e2)) * NGRID + k] = s;
        }
    }
}

// ---------- Fallback: direct scattered writes (if ws too small) ----------
__global__ __launch_bounds__(64)
void mbtr_direct(const float* __restrict__ r, const int* __restrict__ z,
                 const float* __restrict__ grid, float* __restrict__ out)
{
    const int n = blockIdx.x, b = blockIdx.y, t = threadIdx.x;
    __shared__ SmemAcc sm;
    float A[2][4][3] = {{{0.f}}};
    float M[2][4]    = {{0.f}};
    int soff[5];
    mbtr_accum(sm, r, z, grid, b, n, t, A, M, soff);

    const int zn = sm.zl[n];
    float* divout = out + MBTR_ELEMS + (size_t)b * DIV_PER_B;
    #pragma unroll
    for (int h = 0; h < 2; ++h) {
        const int k = t + 64 * h;
        #pragma unroll
        for (int e1 = 0; e1 < 4; ++e1) {
            #pragma unroll
            for (int e2 = 0; e2 < 4; ++e2) {
                float v0 = 0.f, v1 = 0.f, v2 = 0.f;
                if (e1 == zn) { v0 += A[h][e2][0]; v1 += A[h][e2][1]; v2 += A[h][e2][2]; }
                if (e2 == zn) { v0 += A[h][e1][0]; v1 += A[h][e1][1]; v2 += A[h][e1][2]; }
                const size_t off = (size_t)(e1 * 4 + e2) * (NGRID * NATOM * 3)
                                 + (size_t)k * (NATOM * 3) + n * 3;
                divout[off + 0] = v0; divout[off + 1] = v1; divout[off + 2] = v2;
            }
        }
        #pragma unroll
        for (int e2 = 0; e2 < 4; ++e2)
            atomicAdd(&out[((size_t)b * 16 + zn * 4 + e2) * NGRID + k], M[h][e2]);
    }
}

extern "C" void kernel_launch(void* const* d_in, const int* in_sizes, int n_in,
                              void* d_out, int out_size, void* d_ws, size_t ws_size,
                              hipStream_t stream)
{
    const float* r    = (const float*)d_in[0];
    const int*   z    = (const int*)  d_in[1];
    const float* grid = (const float*)d_in[2];
    float* out = (float*)d_out;

    const size_t ws_need = (size_t)NB * NGRID * NATOM * REC * sizeof(float); // 12.6 MB
    if (ws_size >= ws_need) {
        mbtr_k1<<<dim3(NATOM, NB), 64, 0, stream>>>(r, z, grid, (float*)d_ws);
        mbtr_k2<<<dim3(NGRID / 8, NB), 256, 0, stream>>>(z, (const float*)d_ws, out);
    } else {
        (void)hipMemsetAsync(d_out, 0, (size_t)MBTR_ELEMS * sizeof(float), stream);
        mbtr_direct<<<dim3(NATOM, NB), 64, 0, stream>>>(r, z, grid, out);
    }
}

// Round 2
// 87.215 us; speedup vs baseline: 1.1518x; 1.1518x over previous
//
#include <hip/hip_runtime.h>

#define NB     32
#define NATOM  48
#define NGRID  128
#define REC    16
#define KT     4                         /* grid points per K2 block */

#define MBTR_ELEMS (NB*16*NGRID)         /* 65536 */
#define DIV_PER_B  (16*NGRID*NATOM*3)    /* 294912 */
#define PANE       (NGRID*NATOM*3)       /* 18432 floats per (e1,e2) pane */

__device__ __constant__ const float kInvSigma   = 20.0f;                 // 1/0.05
__device__ __constant__ const float kTScale     = 0.84932180580221964f; // sqrt(log2(e)/2)
__device__ __constant__ const float kInvSqrt2Pi = 0.3989422804014327f;

struct SmemAcc {
    float4 pos[NATOM];
    int    zl[NATOM];
    int    order[NATOM];
    float4 recA[NATOM];   // {gf*is*c, gf*gf*is/c, wf*coef, u0}
    float2 recB[NATOM];   // {u1, u2}
};

// A[h][e][c] = sum_{m: z[m]==e, m!=n} s*u_c ; M[h][e] = sum wf*gv
// for grid points k = t and k = t+64. Ballot-based species ordering (no
// serial LDS chains). Block = one (b, n), 64 threads.
__device__ __forceinline__ void mbtr_accum(SmemAcc& sm,
        const float* __restrict__ r, const int* __restrict__ z,
        const float* __restrict__ grid, int b, int n, int t,
        float (&A)[2][4][3], float (&M)[2][4], int (&soff)[5])
{
    const bool isatom = (t < NATOM);
    int myz = -1;
    if (isatom) {
        myz = z[t];
        sm.zl[t] = myz;
        const float* rp = r + ((size_t)b * NATOM + t) * 3;
        sm.pos[t] = make_float4(rp[0], rp[1], rp[2], 0.f);
    }
    const bool nb = isatom && (t != n);
    const unsigned long long m0 = __ballot(nb && myz == 0);
    const unsigned long long m1 = __ballot(nb && myz == 1);
    const unsigned long long m2 = __ballot(nb && myz == 2);
    const unsigned long long m3 = __ballot(nb && myz == 3);
    soff[0] = 0;
    soff[1] = __popcll(m0);
    soff[2] = soff[1] + __popcll(m1);
    soff[3] = soff[2] + __popcll(m2);
    soff[4] = soff[3] + __popcll(m3);
    if (nb) {
        const unsigned long long mm = (myz == 0) ? m0 : (myz == 1) ? m1
                                    : (myz == 2) ? m2 : m3;
        const int rank = __popcll(mm & ((1ull << t) - 1ull));
        sm.order[soff[myz] + rank] = t;
    }
    __syncthreads();

    const float4 rn = sm.pos[n];
    if (t < NATOM - 1) {
        const int    m  = sm.order[t];
        const float4 rm = sm.pos[m];
        const float ddx = rn.x - rm.x, ddy = rn.y - rm.y, ddz = rn.z - rm.z;
        const float d2 = ddx*ddx + ddy*ddy + ddz*ddz;
        const float gf = __builtin_amdgcn_rsqf(d2);   // 1/d
        const float d  = d2 * gf;
        const float wf = __expf(-d);                  // W_SCALE = 1
        const float dx = grid[1] - grid[0];
        const float coef = dx * kInvSqrt2Pi * kInvSigma;
        sm.recA[t] = make_float4(gf * (kInvSigma * kTScale),
                                 gf * gf * (kInvSigma / kTScale),
                                 wf * coef,
                                 ddx * gf);
        sm.recB[t] = make_float2(ddy * gf, ddz * gf);
    }
    __syncthreads();

    const float gkA = grid[t]      * (kInvSigma * kTScale);
    const float gkB = grid[t + 64] * (kInvSigma * kTScale);

    #pragma unroll
    for (int e = 0; e < 4; ++e) {
        const int beg = soff[e], end = soff[e + 1];
        for (int i = beg; i < end; ++i) {
            const float4 ra = sm.recA[i];
            const float2 rb = sm.recB[i];
            {   // k = t
                const float tt  = gkA - ra.x;               // t*c
                const float ex  = exp2f(-tt * tt);          // exp(-t^2/2)
                const float gvw = ra.z * ex;                // wf*gv
                M[0][e] += gvw;
                const float p = gvw * fmaf(tt, ra.y, 1.0f); // -s
                A[0][e][0] = fmaf(-p, ra.w, A[0][e][0]);
                A[0][e][1] = fmaf(-p, rb.x, A[0][e][1]);
                A[0][e][2] = fmaf(-p, rb.y, A[0][e][2]);
            }
            {   // k = t + 64
                const float tt  = gkB - ra.x;
                const float ex  = exp2f(-tt * tt);
                const float gvw = ra.z * ex;
                M[1][e] += gvw;
                const float p = gvw * fmaf(tt, ra.y, 1.0f);
                A[1][e][0] = fmaf(-p, ra.w, A[1][e][0]);
                A[1][e][1] = fmaf(-p, rb.x, A[1][e][1]);
                A[1][e][2] = fmaf(-p, rb.y, A[1][e][2]);
            }
        }
    }
}

// ---------- K1: write compact records to workspace [b][k][n][16] ----------
__global__ __launch_bounds__(64)
void mbtr_k1(const float* __restrict__ r, const int* __restrict__ z,
             const float* __restrict__ grid, float* __restrict__ ws)
{
    const int n = blockIdx.x, b = blockIdx.y, t = threadIdx.x;
    __shared__ SmemAcc sm;
    float A[2][4][3] = {{{0.f}}};
    float M[2][4]    = {{0.f}};
    int soff[5];
    mbtr_accum(sm, r, z, grid, b, n, t, A, M, soff);

    #pragma unroll
    for (int h = 0; h < 2; ++h) {
        const int k = t + 64 * h;
        float4* o4 = (float4*)(ws + (((size_t)b * NGRID + k) * NATOM + n) * REC);
        o4[0] = make_float4(A[h][0][0], A[h][0][1], A[h][0][2], A[h][1][0]);
        o4[1] = make_float4(A[h][1][1], A[h][1][2], A[h][2][0], A[h][2][1]);
        o4[2] = make_float4(A[h][2][2], A[h][3][0], A[h][3][1], A[h][3][2]);
        o4[3] = make_float4(M[h][0],    M[h][1],    M[h][2],    M[h][3]);
    }
}

// ---------- K2: records -> (mbtr, mbtr_div), field-major LDS ----------
__global__ __launch_bounds__(256)
void mbtr_k2(const int* __restrict__ z, const float* __restrict__ ws,
             float* __restrict__ out)
{
    const int kt = blockIdx.x;          // 32 tiles of KT=4 grid points
    const int b  = blockIdx.y;
    const int t  = threadIdx.x;
    const int k0 = kt * KT;

    __shared__ int   zl[NATOM];
    __shared__ float tr[KT * REC * 49];   // [kk][f][49]; [.][.][48] == 0

    if (t < NATOM) zl[t] = z[t];
    if (t < KT * REC) tr[t * 49 + 48] = 0.f;

    // coalesced global float4 load, transposed scatter into LDS
    const float4* w4 = (const float4*)(ws + ((size_t)b * NGRID + k0) * NATOM * REC);
    #pragma unroll
    for (int i = 0; i < 3; ++i) {
        const int q  = t + 256 * i;          // 0..767 over [kk][n][4]
        const float4 v = w4[q];
        const int kk = q / 192;
        const int nn = (q >> 2) % 48;
        const int f0 = (q & 3) * 4;
        float* dst = tr + kk * 784 + f0 * 49 + nn;
        dst[0]   = v.x;
        dst[49]  = v.y;
        dst[98]  = v.z;
        dst[147] = v.w;
    }
    __syncthreads();

    // per-thread float4 output slots: u = t + 256*jj over 576 float4 per k
    int a1[3][4], a2[3][4], obase[3];
    #pragma unroll
    for (int jj = 0; jj < 3; ++jj) {
        const int u = t + 256 * jj;
        if (u < 576) {
            const int pane = u / 36;          // e1*4+e2
            const int w36  = u % 36;          // float4 slot within pane
            const int e1 = pane >> 2, e2 = pane & 3;
            obase[jj] = pane * PANE + w36 * 4;
            #pragma unroll
            for (int s = 0; s < 4; ++s) {
                const int p  = w36 * 4 + s;   // 0..143 over (n,c)
                const int nn = p / 3, c = p - nn * 3;
                a1[jj][s] = (zl[nn] == e1) ? ((e2 * 3 + c) * 49 + nn)
                                           : ((e2 * 3 + c) * 49 + 48);
                a2[jj][s] = (zl[nn] == e2) ? ((e1 * 3 + c) * 49 + nn)
                                           : ((e1 * 3 + c) * 49 + 48);
            }
        }
    }

    // wave 1 owns the mbtr reduction
    int zn_r[12], mbase = 0, e1m = 0, e2m = 0, partm = 0;
    if (t >= 64 && t < 128) {
        const int t2 = t - 64;
        e1m = t2 >> 4; e2m = (t2 >> 2) & 3; partm = t2 & 3;
        #pragma unroll
        for (int i = 0; i < 12; ++i) zn_r[i] = zl[partm + 4 * i];
        mbase = (12 + e2m) * 49 + partm;
    }

    float* divout = out + MBTR_ELEMS + (size_t)b * DIV_PER_B;
    #pragma unroll
    for (int kk = 0; kk < KT; ++kk) {
        const int k = k0 + kk;
        const float* trk = tr + kk * 784;
        #pragma unroll
        for (int jj = 0; jj < 3; ++jj) {
            const int u = t + 256 * jj;
            if (u < 576) {
                float4 v;
                v.x = trk[a1[jj][0]] + trk[a2[jj][0]];
                v.y = trk[a1[jj][1]] + trk[a2[jj][1]];
                v.z = trk[a1[jj][2]] + trk[a2[jj][2]];
                v.w = trk[a1[jj][3]] + trk[a2[jj][3]];
                *(float4*)(divout + obase[jj] + k * 144) = v;
            }
        }
        if (t >= 64 && t < 128) {
            float s = 0.f;
            #pragma unroll
            for (int i = 0; i < 12; ++i)
                s += (zn_r[i] == e1m) ? trk[mbase + 4 * i] : 0.f;
            s += __shfl_xor(s, 1);
            s += __shfl_xor(s, 2);
            if (partm == 0)
                out[((size_t)b * 16 + (e1m * 4 + e2m)) * NGRID + k] = s;
        }
    }
}

// ---------- Fallback: direct scattered writes (if ws too small) ----------
__global__ __launch_bounds__(64)
void mbtr_direct(const float* __restrict__ r, const int* __restrict__ z,
                 const float* __restrict__ grid, float* __restrict__ out)
{
    const int n = blockIdx.x, b = blockIdx.y, t = threadIdx.x;
    __shared__ SmemAcc sm;
    float A[2][4][3] = {{{0.f}}};
    float M[2][4]    = {{0.f}};
    int soff[5];
    mbtr_accum(sm, r, z, grid, b, n, t, A, M, soff);

    const int zn = sm.zl[n];
    float* divout = out + MBTR_ELEMS + (size_t)b * DIV_PER_B;
    #pragma unroll
    for (int h = 0; h < 2; ++h) {
        const int k = t + 64 * h;
        #pragma unroll
        for (int e1 = 0; e1 < 4; ++e1) {
            #pragma unroll
            for (int e2 = 0; e2 < 4; ++e2) {
                float v0 = 0.f, v1 = 0.f, v2 = 0.f;
                if (e1 == zn) { v0 += A[h][e2][0]; v1 += A[h][e2][1]; v2 += A[h][e2][2]; }
                if (e2 == zn) { v0 += A[h][e1][0]; v1 += A[h][e1][1]; v2 += A[h][e1][2]; }
                const size_t off = (size_t)(e1 * 4 + e2) * PANE
                                 + (size_t)k * (NATOM * 3) + n * 3;
                divout[off + 0] = v0; divout[off + 1] = v1; divout[off + 2] = v2;
            }
        }
        #pragma unroll
        for (int e2 = 0; e2 < 4; ++e2)
            atomicAdd(&out[((size_t)b * 16 + zn * 4 + e2) * NGRID + k], M[h][e2]);
    }
}

extern "C" void kernel_launch(void* const* d_in, const int* in_sizes, int n_in,
                              void* d_out, int out_size, void* d_ws, size_t ws_size,
                              hipStream_t stream)
{
    const float* r    = (const float*)d_in[0];
    const int*   z    = (const int*)  d_in[1];
    const float* grid = (const float*)d_in[2];
    float* out = (float*)d_out;

    const size_t ws_need = (size_t)NB * NGRID * NATOM * REC * sizeof(float); // 12.6 MB
    if (ws_size >= ws_need) {
        mbtr_k1<<<dim3(NATOM, NB), 64, 0, stream>>>(r, z, grid, (float*)d_ws);
        mbtr_k2<<<dim3(NGRID / KT, NB), 256, 0, stream>>>(z, (const float*)d_ws, out);
    } else {
        (void)hipMemsetAsync(d_out, 0, (size_t)MBTR_ELEMS * sizeof(float), stream);
        mbtr_direct<<<dim3(NATOM, NB), 64, 0, stream>>>(r, z, grid, out);
    }
}

// Round 3
// 82.636 us; speedup vs baseline: 1.2156x; 1.0554x over previous
//
#include <hip/hip_runtime.h>

#define NB     32
#define NATOM  48
#define NGRID  128
#define KT     8                          /* grid points per block */
#define NTHR   384                        /* 6 waves */

#define MBTR_ELEMS (NB*16*NGRID)          /* 65536 */
#define DIV_PER_B  (16*NGRID*NATOM*3)     /* 294912 */
#define PANE       (NGRID*NATOM*3)        /* 18432 floats per (e1,e2) pane */
#define FSTRIDE    49                     /* padded n-stride per field */
#define KSTRIDE    (16*FSTRIDE)           /* 784 floats per k slab */

// Fused MBTR fwd+div. Block = (b, 8 grid points). Phase 1: thread=(n,k)
// accumulates A_n[e][c] = sum_{m:z[m]=e} s*u_c and M_n[e] = sum wf*gv via a
// species-ordered 48-iteration loop (uniform bounds -> broadcast LDS reads;
// wf folded into the exp2 argument so records need only rsq). Phase 2:
// coalesced float4 expansion of records into the dense (E,E,G,N,3) output
// (verified in R2), mbtr reduction on waves 3-4's idle slot.
__global__ __launch_bounds__(NTHR)
void mbtr_fused(const float* __restrict__ r, const int* __restrict__ z,
                const float* __restrict__ grid, float* __restrict__ out)
{
    const int kt = blockIdx.x, b = blockIdx.y, t = threadIdx.x;
    const int k0 = kt * KT;

    __shared__ float4 pos[NATOM];
    __shared__ int    zl[NATOM];
    __shared__ int    order[NATOM];
    __shared__ int    soff_s[5];
    __shared__ float  Arec[KT * KSTRIDE];   /* [kk][f][49]; [.][.][48] = 0 */

    // ---- setup: wave 0 loads atoms and builds the species-sorted order ----
    if (t < 64) {
        const bool isatom = (t < NATOM);
        int myz = 999;
        if (isatom) {
            myz = z[t];
            zl[t] = myz;
            const float* rp = r + ((size_t)b * NATOM + t) * 3;
            pos[t] = make_float4(rp[0], rp[1], rp[2], 0.f);
        }
        const unsigned long long m0 = __ballot(myz == 0);
        const unsigned long long m1 = __ballot(myz == 1);
        const unsigned long long m2 = __ballot(myz == 2);
        const unsigned long long m3 = __ballot(myz == 3);
        const int c0 = __popcll(m0), c1 = __popcll(m1), c2 = __popcll(m2);
        if (isatom) {
            const unsigned long long mm = (myz == 0) ? m0 : (myz == 1) ? m1
                                        : (myz == 2) ? m2 : m3;
            const int base = (myz == 0) ? 0 : (myz == 1) ? c0
                           : (myz == 2) ? c0 + c1 : c0 + c1 + c2;
            const int rank = __popcll(mm & ((1ull << t) - 1ull));
            order[base + rank] = t;
        }
        if (t == 0) {
            soff_s[0] = 0; soff_s[1] = c0; soff_s[2] = c0 + c1;
            soff_s[3] = c0 + c1 + c2; soff_s[4] = NATOM;
        }
    }
    if (t < KT * 16)   // zero dummy column 48 of every [kk][f] row
        Arec[(t >> 4) * KSTRIDE + (t & 15) * FSTRIDE + NATOM] = 0.f;
    __syncthreads();

    // ---- phase 1: accumulate records, thread = (n, kk) ----
    const int n  = t % NATOM;
    const int kk = t / NATOM;
    const float dx   = grid[1] - grid[0];
    const float coef = dx * (0.3989422804014327f * 20.0f);   // dx/(sqrt(2pi)*sigma)
    const float isc  = 20.0f * 0.84932180580221964f;         // (1/sigma)*sqrt(log2e/2)
    const float tBc  = 20.0f / 0.84932180580221964f;
    const float l2e  = 1.4426950408889634f;
    const float gk   = grid[k0 + kk] * isc;

    float A[4][3] = {{0.f}};
    float M[4]    = {0.f};
    const float4 rn = pos[n];
    int so[5];
    #pragma unroll
    for (int e = 0; e < 5; ++e) so[e] = soff_s[e];

    #pragma unroll
    for (int e = 0; e < 4; ++e) {
        for (int i = so[e]; i < so[e + 1]; ++i) {
            const int    m  = order[i];        // uniform -> broadcast
            const float4 rm = pos[m];          // uniform -> broadcast
            const float ddx = rn.x - rm.x, ddy = rn.y - rm.y, ddz = rn.z - rm.z;
            float d2 = ddx*ddx + ddy*ddy + ddz*ddz;
            const bool self = (m == n);
            d2 = self ? 1.0f : d2;                       // NaN guard
            const float gf  = __builtin_amdgcn_rsqf(d2); // 1/d
            const float d   = d2 * gf;
            const float tt  = gk - gf * isc;             // (grid-1/d)/sigma scaled
            const float arg = fmaf(d, l2e, tt * tt);     // gaussian + wf folded
            const float ex  = exp2f(-arg);
            const float gvw = (self ? 0.f : coef) * ex;  // wf*gv
            M[e] += gvw;
            const float p  = gvw * fmaf(tt, gf * gf * tBc, 1.0f);  // -s
            const float pg = -p * gf;
            A[e][0] = fmaf(pg, ddx, A[e][0]);
            A[e][1] = fmaf(pg, ddy, A[e][1]);
            A[e][2] = fmaf(pg, ddz, A[e][2]);
        }
    }

    {   // store record: field-major stripes, bank = n mod 32 (2-way max, free)
        float* ar = Arec + kk * KSTRIDE + n;
        #pragma unroll
        for (int e = 0; e < 4; ++e) {
            ar[(e * 3 + 0) * FSTRIDE] = A[e][0];
            ar[(e * 3 + 1) * FSTRIDE] = A[e][1];
            ar[(e * 3 + 2) * FSTRIDE] = A[e][2];
            ar[(12 + e)    * FSTRIDE] = M[e];
        }
    }
    __syncthreads();

    // ---- phase 2: coalesced expansion -> out ----
    // div slots: u = t (+384) over 576 float4 per k, fixed across k
    int a1[2][4], a2[2][4], obase[2] = {0, 0};
    #pragma unroll
    for (int jj = 0; jj < 2; ++jj) {
        const int u = t + NTHR * jj;
        if (u < 576) {
            const int pane = u / 36, w36 = u % 36;
            const int e1 = pane >> 2, e2 = pane & 3;
            obase[jj] = pane * PANE + w36 * 4;
            #pragma unroll
            for (int s = 0; s < 4; ++s) {
                const int p = w36 * 4 + s, nn = p / 3, c = p - nn * 3;
                a1[jj][s] = (zl[nn] == e1) ? ((e2 * 3 + c) * FSTRIDE + nn)
                                           : ((e2 * 3 + c) * FSTRIDE + NATOM);
                a2[jj][s] = (zl[nn] == e2) ? ((e1 * 3 + c) * FSTRIDE + nn)
                                           : ((e1 * 3 + c) * FSTRIDE + NATOM);
            }
        }
    }
    const bool do_mbtr = (t >= 192 && t < 320);   // waves 3-4 (idle jj=1 slot)
    int mpane = 0, mkk = 0, me1 = 0, me2 = 0;
    if (do_mbtr) {
        const int t2 = t - 192;
        mpane = t2 >> 3; mkk = t2 & 7;
        me1 = mpane >> 2; me2 = mpane & 3;
    }

    float* divout = out + MBTR_ELEMS + (size_t)b * DIV_PER_B;
    #pragma unroll
    for (int kq = 0; kq < KT; ++kq) {
        const float* trk = Arec + kq * KSTRIDE;
        const int k = k0 + kq;
        #pragma unroll
        for (int jj = 0; jj < 2; ++jj) {
            const int u = t + NTHR * jj;
            if (u < 576) {
                float4 v;
                v.x = trk[a1[jj][0]] + trk[a2[jj][0]];
                v.y = trk[a1[jj][1]] + trk[a2[jj][1]];
                v.z = trk[a1[jj][2]] + trk[a2[jj][2]];
                v.w = trk[a1[jj][3]] + trk[a2[jj][3]];
                *(float4*)(divout + obase[jj] + k * 144) = v;
            }
        }
    }
    if (do_mbtr) {
        const float* tr2 = Arec + mkk * KSTRIDE + (12 + me2) * FSTRIDE;
        float s = 0.f;
        #pragma unroll
        for (int nn = 0; nn < NATOM; ++nn)
            s += (zl[nn] == me1) ? tr2[nn] : 0.f;
        out[(size_t)b * 2048 + mpane * NGRID + k0 + mkk] = s;
    }
}

extern "C" void kernel_launch(void* const* d_in, const int* in_sizes, int n_in,
                              void* d_out, int out_size, void* d_ws, size_t ws_size,
                              hipStream_t stream)
{
    const float* r    = (const float*)d_in[0];
    const int*   z    = (const int*)  d_in[1];
    const float* grid = (const float*)d_in[2];
    float* out = (float*)d_out;
    (void)d_ws; (void)ws_size;

    mbtr_fused<<<dim3(NGRID / KT, NB), NTHR, 0, stream>>>(r, z, grid, out);
}